// Round 9
// baseline (221.931 us; speedup 1.0000x reference)
//
#include <hip/hip_runtime.h>
#include <stdint.h>

typedef unsigned short u16;
typedef short bf16x8 __attribute__((ext_vector_type(8)));
typedef short bf16x4 __attribute__((ext_vector_type(4)));
typedef float f32x4 __attribute__((ext_vector_type(4)));
typedef u16 u16x4 __attribute__((ext_vector_type(4)));

__device__ __forceinline__ u16 f2bf(float f) {
  union { float f; unsigned int u; } v; v.f = f;
  unsigned int r = v.u + 0x7fffu + ((v.u >> 16) & 1u);
  return (u16)(r >> 16);
}

__device__ __forceinline__ void async16(const void* g, void* l) {
  __builtin_amdgcn_global_load_lds(
      (const __attribute__((address_space(1))) unsigned int*)g,
      (__attribute__((address_space(3))) unsigned int*)l, 16, 0, 0);
}

__device__ __forceinline__ f32x4 mfma16x16(bf16x4 a, bf16x4 b, f32x4 c) {
#if __has_builtin(__builtin_amdgcn_mfma_f32_16x16x16bf16_1k)
  return __builtin_amdgcn_mfma_f32_16x16x16bf16_1k(a, b, c, 0, 0, 0);
#else
  asm volatile("v_mfma_f32_16x16x16_bf16 %0, %1, %2, %0\n\ts_nop 7\n\ts_nop 7"
               : "+v"(c) : "v"(a), "v"(b));
  return c;
#endif
}

// ---------------- pose MLP: relu(ang@W1+b1)@W2+b2 -> pose_emb[8][3072] fp32
__global__ void pose_mlp_kernel(const float* __restrict__ ang, const float* __restrict__ W1,
                                const float* __restrict__ b1, const float* __restrict__ W2,
                                const float* __restrict__ b2, float* __restrict__ pose) {
  __shared__ float hid[8][64];
  int t = threadIdx.x;
  for (int idx = t; idx < 512; idx += 256) {
    int b = idx >> 6, j = idx & 63;
    float a = b1[j];
#pragma unroll
    for (int i = 0; i < 3; ++i) a += ang[b * 3 + i] * W1[i * 64 + j];
    hid[b][j] = fmaxf(a, 0.f);
  }
  __syncthreads();
  int idx = blockIdx.x * 256 + t;            // 96*256 == 8*3072 exactly
  int b = idx / 3072, c = idx - b * 3072;
  float a = b2[c];
#pragma unroll
  for (int j = 0; j < 64; ++j) a += hid[b][j] * W2[j * 3072 + c];
  pose[idx] = a;
}

// ---------------- cast fp32 -> bf16 (vectorized)
__global__ void cast_x_kernel(const float4* __restrict__ x, u16x4* __restrict__ y, int n4) {
  int i = blockIdx.x * blockDim.x + threadIdx.x;
  const int stride = gridDim.x * blockDim.x;
  for (; i < n4; i += stride) {
    float4 v = x[i];
    u16x4 o;
    o[0] = f2bf(v.x); o[1] = f2bf(v.y); o[2] = f2bf(v.z); o[3] = f2bf(v.w);
    y[i] = o;
  }
}

// ---------------- transpose + cast: W[K][N] fp32 -> Wt[N][K] bf16
__global__ void transpose_cast_kernel(const float* __restrict__ W, u16* __restrict__ Wt,
                                      int Kdim, int Ncol) {
  __shared__ float tile[64][65];
  const int tx = threadIdx.x, ty = threadIdx.y;
  const int c0 = blockIdx.x * 64, k0 = blockIdx.y * 64;
#pragma unroll
  for (int rr = 0; rr < 16; ++rr) {
    int row = rr * 4 + ty;
    tile[row][tx] = W[(size_t)(k0 + row) * Ncol + c0 + tx];
  }
  __syncthreads();
#pragma unroll
  for (int rr = 0; rr < 16; ++rr) {
    int row = rr * 4 + ty;
    Wt[(size_t)(c0 + row) * Kdim + k0 + tx] = f2bf(tile[tx][row]);
  }
}

// ---------------- 256x256 GEMM, faithful m201 8-phase schedule (T2+T3+T4+T5)
// A[M][K] bf16 row-major, Bt[N][K] bf16 (B^T). BM=BN=256, BK=64.
// 512 thr = 8 waves (2M x 4N); per-wave out 128x64 = acc[8][4].
// HALF-ALIGNED fragment mapping (race fix r9): readA(mh) touches ONLY A-half
// mh (row = mh*128 + wr*64 + mi2*16 + r16); readB(nh) touches ONLY B-half nh
// (row = nh*128 + wc*32 + nj2*16 + r16). Liveness rule: a half staged at
// phase q has last read <= q-2 (stage_q issue overlaps other waves' read_{q-1}).
// Audited: A0 read ph0/staged ph2; B0 ph0/ph3; B1 ph1/ph4; A1 ph2/ph5;
// slot1 symmetric (ph4..ph7 reads, stages ph6,ph7,ph0',ph1').
// vmcnt(6) at ph0/ph4 drains exactly the published slot's 4 halves, leaving
// the 3 newest halves (6 loads) in flight.
// EPI=0: qkv epilogue (+bias+pose, scatter Q/K [B,H,N,D], Vt [B,H,D,N] bf16)
// EPI=1: proj epilogue (+bias, fp32 row-major out)
template <int EPI>
__global__ void __launch_bounds__(512, 2) gemm_8ph_kernel(
    const u16* __restrict__ A, const u16* __restrict__ Bt,
    const float* __restrict__ bias, const float* __restrict__ pose,
    u16* __restrict__ qout, u16* __restrict__ kout, u16* __restrict__ vtout,
    float* __restrict__ cout, int Kdim, int Ncols, int nTilesX) {
  constexpr int BREG = 256 * 64;        // B region offset (u16) within a slot
  constexpr int SLOT = 512 * 64;        // 64 KB per slot
  __shared__ u16 lds[2][SLOT];
  const int t = threadIdx.x, l = t & 63, w = t >> 6;
  const int g = l >> 4, r16 = l & 15;
  const int wr = w >> 2, wc = w & 3;    // 2 M-waves x 4 N-waves
  const int xk = r16 & 7;
  const int nwg = gridDim.x, cpx = nwg >> 3;
  const int swz = (blockIdx.x & 7) * cpx + (blockIdx.x >> 3);
  const int n0 = (swz % nTilesX) * 256, m0 = (swz / nTilesX) * 256;
  const u16* Ab = A + (size_t)m0 * Kdim;
  const u16* Bb = Bt + (size_t)n0 * Kdim;

  // stage one 128-row half (16 KB): hr 0=A0,1=A1,2=B0,3=B1
  auto stage = [&](int slot, int hr, int kt) {
#pragma unroll
    for (int it = 0; it < 2; ++it) {
      int idx = it * 512 + t, row = idx >> 3;
      int seg = (idx & 7) ^ (row & 7);  // pre-swizzled global source (T2)
      const u16* src = (hr < 2) ? Ab + (size_t)(hr * 128 + row) * Kdim + kt + seg * 8
                                : Bb + (size_t)((hr - 2) * 128 + row) * Kdim + kt + seg * 8;
      int dst = ((hr < 2) ? hr * 128 * 64 : BREG + (hr - 2) * 128 * 64) + idx * 8;
      async16(src, &lds[slot][dst]);
    }
  };

  f32x4 acc[8][4] = {};
  bf16x8 aF[4][2], bF0[2][2], bF1[2][2];

  // half-aligned reads: mh/nh select the 128-row half exclusively
  auto readA = [&](int slot, int mh) {
#pragma unroll
    for (int mi2 = 0; mi2 < 4; ++mi2)
#pragma unroll
      for (int ks = 0; ks < 2; ++ks)
        aF[mi2][ks] = *(const bf16x8*)&lds[slot][(mh * 128 + wr * 64 + mi2 * 16 + r16) * 64 +
                                                ((ks * 4 + g) ^ xk) * 8];
  };
  auto readB = [&](int slot, int nh, bf16x8 (&bF)[2][2]) {
#pragma unroll
    for (int nj2 = 0; nj2 < 2; ++nj2)
#pragma unroll
      for (int ks = 0; ks < 2; ++ks)
        bF[nj2][ks] = *(const bf16x8*)&lds[slot][BREG + (nh * 128 + wc * 32 + nj2 * 16 + r16) * 64 +
                                                ((ks * 4 + g) ^ xk) * 8];
  };
  auto bar = [&]() {
    asm volatile("" ::: "memory");
    __builtin_amdgcn_s_barrier();
    asm volatile("" ::: "memory");
  };
  auto lgk = [&]() {
    asm volatile("s_waitcnt lgkmcnt(0)" ::: "memory");
    __builtin_amdgcn_sched_barrier(0);
  };
  auto mmac = [&](int mh, int nh, bf16x8 (&bF)[2][2]) {
    __builtin_amdgcn_s_setprio(1);
#pragma unroll
    for (int ks = 0; ks < 2; ++ks)
#pragma unroll
      for (int mi2 = 0; mi2 < 4; ++mi2)
#pragma unroll
        for (int nj2 = 0; nj2 < 2; ++nj2)
          acc[mh * 4 + mi2][nh * 2 + nj2] = __builtin_amdgcn_mfma_f32_16x16x32_bf16(
              aF[mi2][ks], bF[nj2][ks], acc[mh * 4 + mi2][nh * 2 + nj2], 0, 0, 0);
    __builtin_amdgcn_s_setprio(0);
  };

  const int nIter = Kdim >> 7;          // 2 K-tiles per iteration
  // prologue: tile0 -> slot0 (A0,B0,B1,A1), tile1 -> slot1 (A0,B0) = 12 loads
  stage(0, 0, 0); stage(0, 2, 0); stage(0, 3, 0); stage(0, 1, 0);
  stage(1, 0, 64); stage(1, 2, 64);

  for (int i = 0; i < nIter; ++i) {
    const bool pf = (i + 1 < nIter);
    const int k1 = (2 * i + 1) << 6, k2 = (2 * i + 2) << 6, k3 = (2 * i + 3) << 6;
    // ---- phase 0 (K-tile 2i, slot0): publish slot0
    stage(1, 3, k1);
    __builtin_amdgcn_sched_barrier(0);
    asm volatile("s_waitcnt vmcnt(6)" ::: "memory");
    bar();
    readA(0, 0); readB(0, 0, bF0);      // A0, B0 only
    lgk();
    mmac(0, 0, bF0);
    // ---- phase 1
    stage(1, 1, k1);
    bar();
    readB(0, 1, bF1);                   // B1 only
    lgk();
    mmac(0, 1, bF1);
    // ---- phase 2
    if (pf) stage(0, 0, k2);            // A0: last read ph0 -> safe
    bar();
    readA(0, 1);                        // A1 only
    lgk();
    mmac(1, 0, bF0);
    // ---- phase 3
    if (pf) stage(0, 2, k2);            // B0: last read ph0 -> safe
    bar();
    lgk();
    mmac(1, 1, bF1);
    // ---- phase 4 (K-tile 2i+1, slot1): publish slot1
    if (pf) stage(0, 3, k2);            // B1: last read ph1 -> safe
    __builtin_amdgcn_sched_barrier(0);
    if (pf) asm volatile("s_waitcnt vmcnt(6)" ::: "memory");
    else    asm volatile("s_waitcnt vmcnt(0)" ::: "memory");
    bar();
    readA(1, 0); readB(1, 0, bF0);
    lgk();
    mmac(0, 0, bF0);
    // ---- phase 5
    if (pf) stage(0, 1, k2);            // A1: last read ph2 -> safe
    bar();
    readB(1, 1, bF1);
    lgk();
    mmac(0, 1, bF1);
    // ---- phase 6
    if (pf) stage(1, 0, k3);            // s1.A0: last read ph4 -> safe
    bar();
    readA(1, 1);
    lgk();
    mmac(1, 0, bF0);
    // ---- phase 7
    if (pf) stage(1, 2, k3);            // s1.B0: last read ph4 -> safe
    bar();
    lgk();
    mmac(1, 1, bF1);
  }

#pragma unroll
  for (int mi = 0; mi < 8; ++mi)
#pragma unroll
    for (int nj = 0; nj < 4; ++nj)
#pragma unroll
      for (int r = 0; r < 4; ++r) {
        int row = m0 + (mi >> 2) * 128 + wr * 64 + (mi & 3) * 16 + g * 4 + r;
        int col = n0 + (nj >> 1) * 128 + wc * 32 + (nj & 1) * 16 + r16;
        float v = acc[mi][nj][r] + bias[col];
        if (EPI == 0) {
          int b = row >> 10, n = row & 1023;
          v += pose[b * 3072 + col];
          u16 hv = f2bf(v);
          int three = col >> 10, hh = (col >> 6) & 15, d = col & 63;
          size_t bhh = (size_t)(b * 16 + hh);
          if (three == 0)      qout[(bhh * 1024 + n) * 64 + d] = hv;
          else if (three == 1) kout[(bhh * 1024 + n) * 64 + d] = hv;
          else                 vtout[(bhh * 64 + d) * 1024 + n] = hv;
        } else {
          cout[(size_t)row * Ncols + col] = v;
        }
      }
}

// ---------------- attention: per block = (b,h, 64 q-rows), 4 waves x 16 q-rows
// swapped QK^T: S^T = mfma(K, Q) -> lane owns q = l&15; P feeds 16x16x16 PV directly.
__global__ void __launch_bounds__(256) attn_kernel(
    const u16* __restrict__ Qb, const u16* __restrict__ Kb,
    const u16* __restrict__ Vtb, u16* __restrict__ aout) {
  __shared__ u16 ldsK[64][72];
  __shared__ u16 ldsV[64][72];
  const int t = threadIdx.x, l = t & 63, w = t >> 6;
  const int g = l >> 4, r16 = l & 15;
  const int bh = blockIdx.x >> 4, qt = blockIdx.x & 15;
  const int b = bh >> 4, h = bh & 15;
  const int q0 = qt * 64 + w * 16;
  const u16* Qp = Qb + ((size_t)bh * 1024 + q0 + r16) * 64;
  bf16x8 qreg0 = *(const bf16x8*)(Qp + g * 8);
  bf16x8 qreg1 = *(const bf16x8*)(Qp + 32 + g * 8);
  const u16* Kbase = Kb + (size_t)bh * 1024 * 64;
  const u16* Vbase = Vtb + (size_t)bh * 64 * 1024;
  float m = -1e30f, rs = 0.f;
  f32x4 o[4] = {};
  for (int key0 = 0; key0 < 1024; key0 += 64) {
#pragma unroll
    for (int ii = 0; ii < 2; ++ii) {
      int idx = ii * 256 + t, row = idx >> 3, seg = idx & 7;
      *(bf16x8*)&ldsK[row][seg * 8] = *(const bf16x8*)(Kbase + (size_t)(key0 + row) * 64 + seg * 8);
      *(bf16x8*)&ldsV[row][seg * 8] = *(const bf16x8*)(Vbase + (size_t)row * 1024 + key0 + seg * 8);
    }
    __syncthreads();
    f32x4 s[4] = {};
#pragma unroll
    for (int f = 0; f < 4; ++f) {
      bf16x8 ak0 = *(const bf16x8*)&ldsK[f * 16 + r16][g * 8];
      s[f] = __builtin_amdgcn_mfma_f32_16x16x32_bf16(ak0, qreg0, s[f], 0, 0, 0);
      bf16x8 ak1 = *(const bf16x8*)&ldsK[f * 16 + r16][32 + g * 8];
      s[f] = __builtin_amdgcn_mfma_f32_16x16x32_bf16(ak1, qreg1, s[f], 0, 0, 0);
    }
    float mt = -1e30f;
#pragma unroll
    for (int f = 0; f < 4; ++f)
#pragma unroll
      for (int r = 0; r < 4; ++r) { s[f][r] *= 0.125f; mt = fmaxf(mt, s[f][r]); }
    mt = fmaxf(mt, __shfl_xor(mt, 16));
    mt = fmaxf(mt, __shfl_xor(mt, 32));
    float mnew = fmaxf(m, mt);
    float alpha = __expf(m - mnew);
    float rt = 0.f;
    bf16x4 pa[4];
#pragma unroll
    for (int f = 0; f < 4; ++f) {
#pragma unroll
      for (int r = 0; r < 4; ++r) {
        float p = __expf(s[f][r] - mnew);
        rt += p;
        pa[f][r] = (short)f2bf(p);
      }
    }
    rt += __shfl_xor(rt, 16);
    rt += __shfl_xor(rt, 32);
    rs = rs * alpha + rt;
    m = mnew;
    float ar[4];
#pragma unroll
    for (int r = 0; r < 4; ++r) ar[r] = __shfl(alpha, (l & 48) | (g * 4 + r));
#pragma unroll
    for (int nf = 0; nf < 4; ++nf)
#pragma unroll
      for (int r = 0; r < 4; ++r) o[nf][r] *= ar[r];
#pragma unroll
    for (int s4 = 0; s4 < 4; ++s4)
#pragma unroll
      for (int nf = 0; nf < 4; ++nf) {
        bf16x4 bv = *(const bf16x4*)&ldsV[nf * 16 + r16][s4 * 16 + g * 4];
        o[nf] = mfma16x16(pa[s4], bv, o[nf]);
      }
    __syncthreads();
  }
  float rr[4];
#pragma unroll
  for (int r = 0; r < 4; ++r) rr[r] = __shfl(1.0f / rs, (l & 48) | (g * 4 + r));
#pragma unroll
  for (int nf = 0; nf < 4; ++nf)
#pragma unroll
    for (int r = 0; r < 4; ++r) {
      int qq = qt * 64 + w * 16 + g * 4 + r;
      int d = nf * 16 + r16;
      aout[((size_t)b * 1024 + qq) * 1024 + h * 64 + d] = f2bf(o[nf][r] * rr[r]);
    }
}

extern "C" void kernel_launch(void* const* d_in, const int* in_sizes, int n_in,
                              void* d_out, int out_size, void* d_ws, size_t ws_size,
                              hipStream_t stream) {
  (void)in_sizes; (void)n_in; (void)out_size; (void)ws_size;
  const float* x     = (const float*)d_in[0];
  const float* ang   = (const float*)d_in[1];
  const float* Wqkv  = (const float*)d_in[2];
  const float* bqkv  = (const float*)d_in[3];
  const float* W1    = (const float*)d_in[4];
  const float* b1    = (const float*)d_in[5];
  const float* W2    = (const float*)d_in[6];
  const float* b2    = (const float*)d_in[7];
  const float* Wproj = (const float*)d_in[8];
  const float* bproj = (const float*)d_in[9];
  float* out = (float*)d_out;
  char* ws = (char*)d_ws;

  u16* xh     = (u16*)(ws);                                 // 16 MB; reused as attn_out
  u16* wqkvt  = (u16*)(ws + (size_t)16 * 1024 * 1024);      // 6 MB
  u16* wprojt = (u16*)(ws + (size_t)22 * 1024 * 1024);      // 2 MB
  float* pose = (float*)(ws + (size_t)24 * 1024 * 1024);    // 96 KB
  u16* Qb     = (u16*)(ws + (size_t)25 * 1024 * 1024);      // 16 MB
  u16* Kb     = (u16*)(ws + (size_t)41 * 1024 * 1024);      // 16 MB
  u16* Vtb    = (u16*)(ws + (size_t)57 * 1024 * 1024);      // 16 MB

  pose_mlp_kernel<<<96, 256, 0, stream>>>(ang, W1, b1, W2, b2, pose);
  cast_x_kernel<<<2048, 256, 0, stream>>>((const float4*)x, (u16x4*)xh, 8 * 1024 * 1024 / 4);
  transpose_cast_kernel<<<dim3(48, 16), dim3(64, 4), 0, stream>>>(Wqkv, wqkvt, 1024, 3072);
  transpose_cast_kernel<<<dim3(16, 16), dim3(64, 4), 0, stream>>>(Wproj, wprojt, 1024, 1024);
  // QKV: M=8192 (32 tiles of 256), N=3072 (12 tiles of 256) -> 384 blocks
  gemm_8ph_kernel<0><<<384, 512, 0, stream>>>(xh, wqkvt, bqkv, pose,
                                              Qb, Kb, Vtb, nullptr, 1024, 3072, 12);
  attn_kernel<<<2048, 256, 0, stream>>>(Qb, Kb, Vtb, xh);
  // proj: M=8192 (32 tiles), N=1024 (4 tiles of 256) -> 128 blocks
  gemm_8ph_kernel<1><<<128, 512, 0, stream>>>(xh, wprojt, bproj, nullptr,
                                              nullptr, nullptr, nullptr, out, 1024, 1024, 4);
}

// Round 10
// 197.971 us; speedup vs baseline: 1.1210x; 1.1210x over previous
//
#include <hip/hip_runtime.h>
#include <stdint.h>

typedef unsigned short u16;
typedef short bf16x8 __attribute__((ext_vector_type(8)));
typedef short bf16x4 __attribute__((ext_vector_type(4)));
typedef float f32x4 __attribute__((ext_vector_type(4)));
typedef u16 u16x4 __attribute__((ext_vector_type(4)));

__device__ __forceinline__ u16 f2bf(float f) {
  union { float f; unsigned int u; } v; v.f = f;
  unsigned int r = v.u + 0x7fffu + ((v.u >> 16) & 1u);
  return (u16)(r >> 16);
}

__device__ __forceinline__ void async16(const void* g, void* l) {
  __builtin_amdgcn_global_load_lds(
      (const __attribute__((address_space(1))) unsigned int*)g,
      (__attribute__((address_space(3))) unsigned int*)l, 16, 0, 0);
}

__device__ __forceinline__ f32x4 mfma16x16(bf16x4 a, bf16x4 b, f32x4 c) {
#if __has_builtin(__builtin_amdgcn_mfma_f32_16x16x16bf16_1k)
  return __builtin_amdgcn_mfma_f32_16x16x16bf16_1k(a, b, c, 0, 0, 0);
#else
  asm volatile("v_mfma_f32_16x16x16_bf16 %0, %1, %2, %0\n\ts_nop 7\n\ts_nop 7"
               : "+v"(c) : "v"(a), "v"(b));
  return c;
#endif
}

// ---------------- front kernel: pose MLP + x cast + both weight transposes,
// fused into one launch (independent inputs, disjoint outputs), partitioned
// by blockIdx range: [0,96) pose | [96,1120) cast | [1120,1888) Wqkv^T |
// [1888,2144) Wproj^T.
__global__ void __launch_bounds__(256) front_kernel(
    const float4* __restrict__ x4, u16x4* __restrict__ xh4,
    const float* __restrict__ ang, const float* __restrict__ W1,
    const float* __restrict__ b1, const float* __restrict__ W2,
    const float* __restrict__ b2, float* __restrict__ pose,
    const float* __restrict__ Wqkv, u16* __restrict__ wqkvt,
    const float* __restrict__ Wproj, u16* __restrict__ wprojt) {
  __shared__ float sh[64 * 65];
  const int fb = blockIdx.x, t = threadIdx.x;
  if (fb < 96) {
    // ---- pose MLP: hid in sh[0..511]
    float (*hid)[64] = (float (*)[64])sh;
    for (int idx = t; idx < 512; idx += 256) {
      int b = idx >> 6, j = idx & 63;
      float a = b1[j];
#pragma unroll
      for (int i = 0; i < 3; ++i) a += ang[b * 3 + i] * W1[i * 64 + j];
      hid[b][j] = fmaxf(a, 0.f);
    }
    __syncthreads();
    int idx = fb * 256 + t;                  // 96*256 == 8*3072 exactly
    int b = idx / 3072, c = idx - b * 3072;
    float a = b2[c];
#pragma unroll
    for (int j = 0; j < 64; ++j) a += hid[b][j] * W2[j * 3072 + c];
    pose[idx] = a;
  } else if (fb < 1120) {
    // ---- cast x fp32 -> bf16 (grid-stride over 2M float4)
    const int n4 = 8 * 1024 * 1024 / 4;
    int i = (fb - 96) * 256 + t;
    const int stride = 1024 * 256;
    for (; i < n4; i += stride) {
      float4 v = x4[i];
      u16x4 o;
      o[0] = f2bf(v.x); o[1] = f2bf(v.y); o[2] = f2bf(v.z); o[3] = f2bf(v.w);
      xh4[i] = o;
    }
  } else {
    // ---- transpose + cast: W[K][N] fp32 -> Wt[N][K] bf16
    const float* W; u16* Wt; int Kdim, Ncol, bx, by;
    if (fb < 1888) { W = Wqkv; Wt = wqkvt; Kdim = 1024; Ncol = 3072;
                     int b = fb - 1120; bx = b % 48; by = b / 48; }
    else           { W = Wproj; Wt = wprojt; Kdim = 1024; Ncol = 1024;
                     int b = fb - 1888; bx = b % 16; by = b / 16; }
    float (*tile)[65] = (float (*)[65])sh;
    const int tx = t & 63, ty = t >> 6;
    const int c0 = bx * 64, k0 = by * 64;
#pragma unroll
    for (int rr = 0; rr < 16; ++rr) {
      int row = rr * 4 + ty;
      tile[row][tx] = W[(size_t)(k0 + row) * Ncol + c0 + tx];
    }
    __syncthreads();
#pragma unroll
    for (int rr = 0; rr < 16; ++rr) {
      int row = rr * 4 + ty;
      Wt[(size_t)(c0 + row) * Kdim + k0 + tx] = f2bf(tile[tx][row]);
    }
  }
}

// ---------------- 256x128 GEMM, 2-phase counted-vmcnt schedule (r6, measured
// best: 109 us QKV). A[M][K] bf16 row-major, Bt[N][K] bf16 (B^T).
// BM=256, BN=128, BK=64. 512 threads = 8 waves (4M x 2N); per-wave 64x64.
// LDS: dbuf x (A 256x64 + B 128x64) = 96 KB; T2 XOR swizzle both-sides.
// Tile boundary waits vmcnt(2): next tile's loads stay in flight (T4).
template <int EPI>
__global__ void __launch_bounds__(512) gemm8_kernel(
    const u16* __restrict__ A, const u16* __restrict__ Bt,
    const float* __restrict__ bias, const float* __restrict__ pose,
    u16* __restrict__ qout, u16* __restrict__ kout, u16* __restrict__ vtout,
    float* __restrict__ cout, int Kdim, int Ncols, int nTilesX) {
  constexpr int BOFF = 256 * 64;        // B region offset in LDS (u16 units)
  __shared__ u16 lds[2][(256 + 128) * 64];
  const int t = threadIdx.x, l = t & 63, w = t >> 6;
  const int g = l >> 4, r16 = l & 15;
  const int wr = w >> 1, wc = w & 1;    // 4 M-waves x 2 N-waves
  const int xk = r16 & 7;               // per-lane XOR key for swizzled reads
  const int nwg = gridDim.x, cpx = nwg >> 3;
  const int swz = (blockIdx.x & 7) * cpx + (blockIdx.x >> 3);
  const int n0 = (swz % nTilesX) * 128, m0 = (swz / nTilesX) * 256;
  const u16* Ab = A + (size_t)m0 * Kdim;
  const u16* Bb = Bt + (size_t)n0 * Kdim;

  auto stage = [&](int buf, int kt, int st) {
#pragma unroll
    for (int it = 0; it < 2; ++it) {
      int idx = it * 512 + t, row = idx >> 3;
      int seg = (idx & 7) ^ (row & 7);  // pre-swizzled global source (T2)
      if (st < 2)
        async16(Ab + (size_t)(st * 128 + row) * Kdim + kt + seg * 8,
                &lds[buf][st * 128 * 64 + idx * 8]);
      else
        async16(Bb + (size_t)row * Kdim + kt + seg * 8, &lds[buf][BOFF + idx * 8]);
    }
  };

  f32x4 acc[4][4] = {};
  const int nT = Kdim >> 6;
#pragma unroll
  for (int st = 0; st < 3; ++st) stage(0, 0, st);

  for (int tt = 0; tt < nT; ++tt) {
    const int cur = tt & 1, nxt = cur ^ 1;
    const bool pf = (tt + 1 < nT);
    const int ktn = (tt + 1) << 6;
    // ---- phase 0: publish cur, compute mi 0..1
    if (pf) {
      stage(nxt, ktn, 0);
      __builtin_amdgcn_sched_barrier(0);
      asm volatile("s_waitcnt vmcnt(2)" ::: "memory");
    } else {
      asm volatile("s_waitcnt vmcnt(0)" ::: "memory");
    }
    __builtin_amdgcn_s_barrier();
    __builtin_amdgcn_sched_barrier(0);
    bf16x8 bfr[4][2], af[2][2];
#pragma unroll
    for (int nj = 0; nj < 4; ++nj)
#pragma unroll
      for (int ks = 0; ks < 2; ++ks)
        bfr[nj][ks] = *(const bf16x8*)&lds[cur][BOFF + (wc * 64 + nj * 16 + r16) * 64 +
                                               ((ks * 4 + g) ^ xk) * 8];
#pragma unroll
    for (int mi = 0; mi < 2; ++mi)
#pragma unroll
      for (int ks = 0; ks < 2; ++ks)
        af[mi][ks] = *(const bf16x8*)&lds[cur][(wr * 64 + mi * 16 + r16) * 64 +
                                              ((ks * 4 + g) ^ xk) * 8];
    __builtin_amdgcn_s_setprio(1);
#pragma unroll
    for (int ks = 0; ks < 2; ++ks)
#pragma unroll
      for (int mi = 0; mi < 2; ++mi)
#pragma unroll
        for (int nj = 0; nj < 4; ++nj)
          acc[mi][nj] = __builtin_amdgcn_mfma_f32_16x16x32_bf16(af[mi][ks], bfr[nj][ks],
                                                                acc[mi][nj], 0, 0, 0);
    __builtin_amdgcn_s_setprio(0);
    // ---- phase 1: compute mi 2..3
    if (pf) { stage(nxt, ktn, 1); stage(nxt, ktn, 2); }
    bf16x8 af2[2][2];
#pragma unroll
    for (int mi = 0; mi < 2; ++mi)
#pragma unroll
      for (int ks = 0; ks < 2; ++ks)
        af2[mi][ks] = *(const bf16x8*)&lds[cur][(wr * 64 + (mi + 2) * 16 + r16) * 64 +
                                               ((ks * 4 + g) ^ xk) * 8];
    __builtin_amdgcn_s_setprio(1);
#pragma unroll
    for (int ks = 0; ks < 2; ++ks)
#pragma unroll
      for (int mi = 0; mi < 2; ++mi)
#pragma unroll
        for (int nj = 0; nj < 4; ++nj)
          acc[mi + 2][nj] = __builtin_amdgcn_mfma_f32_16x16x32_bf16(af2[mi][ks], bfr[nj][ks],
                                                                    acc[mi + 2][nj], 0, 0, 0);
    __builtin_amdgcn_s_setprio(0);
    __builtin_amdgcn_s_barrier();   // end-of-tile: protects cur from next stages
  }

#pragma unroll
  for (int mi = 0; mi < 4; ++mi)
#pragma unroll
    for (int nj = 0; nj < 4; ++nj)
#pragma unroll
      for (int r = 0; r < 4; ++r) {
        int row = m0 + wr * 64 + mi * 16 + g * 4 + r;
        int col = n0 + wc * 64 + nj * 16 + r16;
        float v = acc[mi][nj][r] + bias[col];
        if (EPI == 0) {
          int b = row >> 10, n = row & 1023;
          v += pose[b * 3072 + col];
          u16 hv = f2bf(v);
          int three = col >> 10, hh = (col >> 6) & 15, d = col & 63;
          size_t bhh = (size_t)(b * 16 + hh);
          if (three == 0)      qout[(bhh * 1024 + n) * 64 + d] = hv;
          else if (three == 1) kout[(bhh * 1024 + n) * 64 + d] = hv;
          else                 vtout[(bhh * 64 + d) * 1024 + n] = hv;
        } else {
          cout[(size_t)row * Ncols + col] = v;
        }
      }
}

// ---------------- attention: per block = (b,h, 64 q-rows), 4 waves x 16 q-rows
// swapped QK^T: S^T = mfma(K, Q) -> lane owns q = l&15; P feeds 16x16x16 PV.
// XCD-locality remap (r10): bh = blk&127, qt = blk>>7 -> all 16 q-tile blocks
// of one (b,h) have blockIdx == bh (mod 8) -> same XCD under round-robin ->
// that XCD's L2 holds its 16 bh's K/V (16 x 256KB = 4MB) -> KV HBM ~1x not 8x.
__global__ void __launch_bounds__(256) attn_kernel(
    const u16* __restrict__ Qb, const u16* __restrict__ Kb,
    const u16* __restrict__ Vtb, u16* __restrict__ aout) {
  __shared__ u16 ldsK[64][72];
  __shared__ u16 ldsV[64][72];
  const int t = threadIdx.x, l = t & 63, w = t >> 6;
  const int g = l >> 4, r16 = l & 15;
  const int blk = blockIdx.x;
  const int bh = blk & 127, qt = blk >> 7;   // XCD-locality remap
  const int b = bh >> 4, h = bh & 15;
  const int q0 = qt * 64 + w * 16;
  const u16* Qp = Qb + ((size_t)bh * 1024 + q0 + r16) * 64;
  bf16x8 qreg0 = *(const bf16x8*)(Qp + g * 8);
  bf16x8 qreg1 = *(const bf16x8*)(Qp + 32 + g * 8);
  const u16* Kbase = Kb + (size_t)bh * 1024 * 64;
  const u16* Vbase = Vtb + (size_t)bh * 64 * 1024;
  float m = -1e30f, rs = 0.f;
  f32x4 o[4] = {};
  for (int key0 = 0; key0 < 1024; key0 += 64) {
#pragma unroll
    for (int ii = 0; ii < 2; ++ii) {
      int idx = ii * 256 + t, row = idx >> 3, seg = idx & 7;
      *(bf16x8*)&ldsK[row][seg * 8] = *(const bf16x8*)(Kbase + (size_t)(key0 + row) * 64 + seg * 8);
      *(bf16x8*)&ldsV[row][seg * 8] = *(const bf16x8*)(Vbase + (size_t)row * 1024 + key0 + seg * 8);
    }
    __syncthreads();
    f32x4 s[4] = {};
#pragma unroll
    for (int f = 0; f < 4; ++f) {
      bf16x8 ak0 = *(const bf16x8*)&ldsK[f * 16 + r16][g * 8];
      s[f] = __builtin_amdgcn_mfma_f32_16x16x32_bf16(ak0, qreg0, s[f], 0, 0, 0);
      bf16x8 ak1 = *(const bf16x8*)&ldsK[f * 16 + r16][32 + g * 8];
      s[f] = __builtin_amdgcn_mfma_f32_16x16x32_bf16(ak1, qreg1, s[f], 0, 0, 0);
    }
    float mt = -1e30f;
#pragma unroll
    for (int f = 0; f < 4; ++f)
#pragma unroll
      for (int r = 0; r < 4; ++r) { s[f][r] *= 0.125f; mt = fmaxf(mt, s[f][r]); }
    mt = fmaxf(mt, __shfl_xor(mt, 16));
    mt = fmaxf(mt, __shfl_xor(mt, 32));
    float mnew = fmaxf(m, mt);
    float alpha = __expf(m - mnew);
    float rt = 0.f;
    bf16x4 pa[4];
#pragma unroll
    for (int f = 0; f < 4; ++f) {
#pragma unroll
      for (int r = 0; r < 4; ++r) {
        float p = __expf(s[f][r] - mnew);
        rt += p;
        pa[f][r] = (short)f2bf(p);
      }
    }
    rt += __shfl_xor(rt, 16);
    rt += __shfl_xor(rt, 32);
    rs = rs * alpha + rt;
    m = mnew;
    float ar[4];
#pragma unroll
    for (int r = 0; r < 4; ++r) ar[r] = __shfl(alpha, (l & 48) | (g * 4 + r));
#pragma unroll
    for (int nf = 0; nf < 4; ++nf)
#pragma unroll
      for (int r = 0; r < 4; ++r) o[nf][r] *= ar[r];
#pragma unroll
    for (int s4 = 0; s4 < 4; ++s4)
#pragma unroll
      for (int nf = 0; nf < 4; ++nf) {
        bf16x4 bv = *(const bf16x4*)&ldsV[nf * 16 + r16][s4 * 16 + g * 4];
        o[nf] = mfma16x16(pa[s4], bv, o[nf]);
      }
    __syncthreads();
  }
  float rr[4];
#pragma unroll
  for (int r = 0; r < 4; ++r) rr[r] = __shfl(1.0f / rs, (l & 48) | (g * 4 + r));
#pragma unroll
  for (int nf = 0; nf < 4; ++nf)
#pragma unroll
    for (int r = 0; r < 4; ++r) {
      int qq = qt * 64 + w * 16 + g * 4 + r;
      int d = nf * 16 + r16;
      aout[((size_t)b * 1024 + qq) * 1024 + h * 64 + d] = f2bf(o[nf][r] * rr[r]);
    }
}

extern "C" void kernel_launch(void* const* d_in, const int* in_sizes, int n_in,
                              void* d_out, int out_size, void* d_ws, size_t ws_size,
                              hipStream_t stream) {
  (void)in_sizes; (void)n_in; (void)out_size; (void)ws_size;
  const float* x     = (const float*)d_in[0];
  const float* ang   = (const float*)d_in[1];
  const float* Wqkv  = (const float*)d_in[2];
  const float* bqkv  = (const float*)d_in[3];
  const float* W1    = (const float*)d_in[4];
  const float* b1    = (const float*)d_in[5];
  const float* W2    = (const float*)d_in[6];
  const float* b2    = (const float*)d_in[7];
  const float* Wproj = (const float*)d_in[8];
  const float* bproj = (const float*)d_in[9];
  float* out = (float*)d_out;
  char* ws = (char*)d_ws;

  u16* xh     = (u16*)(ws);                                 // 16 MB; reused as attn_out
  u16* wqkvt  = (u16*)(ws + (size_t)16 * 1024 * 1024);      // 6 MB
  u16* wprojt = (u16*)(ws + (size_t)22 * 1024 * 1024);      // 2 MB
  float* pose = (float*)(ws + (size_t)24 * 1024 * 1024);    // 96 KB
  u16* Qb     = (u16*)(ws + (size_t)25 * 1024 * 1024);      // 16 MB
  u16* Kb     = (u16*)(ws + (size_t)41 * 1024 * 1024);      // 16 MB
  u16* Vtb    = (u16*)(ws + (size_t)57 * 1024 * 1024);      // 16 MB

  front_kernel<<<2144, 256, 0, stream>>>((const float4*)x, (u16x4*)xh,
                                         ang, W1, b1, W2, b2, pose,
                                         Wqkv, wqkvt, Wproj, wprojt);
  // QKV: M=8192 (32 tiles of 256), N=3072 (24 tiles of 128) -> 768 blocks = 3 rounds
  gemm8_kernel<0><<<768, 512, 0, stream>>>(xh, wqkvt, bqkv, pose,
                                           Qb, Kb, Vtb, nullptr, 1024, 3072, 24);
  attn_kernel<<<2048, 256, 0, stream>>>(Qb, Kb, Vtb, xh);
  // proj: M=8192 (32 tiles), N=1024 (8 tiles of 128) -> 256 blocks = 1 round
  gemm8_kernel<1><<<256, 512, 0, stream>>>(xh, wprojt, bproj, nullptr,
                                           nullptr, nullptr, nullptr, out, 1024, 1024, 8);
}